// Round 8
// baseline (929.269 us; speedup 1.0000x reference)
//
#include <hip/hip_runtime.h>
#include <hip/hip_bf16.h>
#include <hip/hip_fp16.h>

namespace {

constexpr int kB = 2;
constexpr int kL = 2048;
constexpr int kD = 1024;
constexpr int kN = 16;
constexpr int kNH = kN / 2;                 // half2 pairs
constexpr int kTPB = 256;
constexpr int kNDBLK = kD / kTPB;           // 4 blocks cover D
constexpr int kNSEQ = kB * kNDBLK;          // 8 independent (b, dblk) sequences
constexpr int kBD = kB * kD;                // 2048
constexpr int kBDN = kBD * kN;              // 32768
constexpr int kW = 16;                      // lookback window
constexpr float kLog2e = 1.4426950408889634f;

// ln(n+1) for n=0..15 (log-domain fast check: no transcendentals)
__device__ __constant__ float kLn[kN] = {
    0.0f,        0.69314718f, 1.09861229f, 1.38629436f,
    1.60943791f, 1.79175947f, 1.94591015f, 2.07944154f,
    2.19722458f, 2.30258509f, 2.39789527f, 2.48490665f,
    2.56494936f, 2.63905733f, 2.70805020f, 2.77258872f};

__device__ __forceinline__ float ex2(float v) {
  return __builtin_amdgcn_exp2f(v);
}

// a[n] = e1^(n+1), log-depth (4 squares + 11 muls)
__device__ __forceinline__ void build_pows(float e1, float* a) {
  const float p2 = e1 * e1;
  const float p4 = p2 * p2;
  const float p8 = p4 * p4;
  a[0] = e1;      a[1] = p2;      a[2] = p2 * e1;  a[3] = p4;
  a[4] = p4 * e1; a[5] = p4 * p2; a[6] = p4 * a[2]; a[7] = p8;
  a[8] = p8 * e1; a[9] = p8 * p2; a[10] = p8 * a[2]; a[11] = p8 * p4;
  a[12] = p8 * a[4]; a[13] = p8 * a[5]; a[14] = p8 * a[6]; a[15] = p8 * p8;
}

__device__ __forceinline__ bool fast_check(const float* __restrict__ al) {
  const float a0 = al[0];
  bool f = true;
#pragma unroll
  for (int n = 1; n < kN; ++n)
    f = f && (fabsf(al[n] - a0 - kLn[n]) <= 1e-3f);
  return __all(f);
}

// pow_n(t) = exp(An * t) for all n. FAST: An = (n+1)*A0 -> e1^(n+1).
template <bool FAST>
__device__ __forceinline__ void make_pows(float t, float A0,
                                          const float (&AnL)[kN], float* a) {
  if (FAST) {
    build_pows(ex2(t * A0), a);
  } else {
#pragma unroll
    for (int n = 0; n < kN; ++n) a[n] = ex2(t * AnL[n]);
  }
}

// ======================= single-pass decoupled lookback =======================
// bid = c*kNSEQ + seq  (ascending dispatch => ascending chunk order)
// Flags[bid]: 0 = none, 1 = aggregate ready, 2 = inclusive prefix ready
// AggT[bid][tid]: chunk dt-sum (f32)     AggS[bid][q][tid]: chunk finals (half2)
// PreS[bid][q][tid]: inclusive prefix states (half2)

template <int C, bool FAST>
__device__ __forceinline__ void ssm_body(
    const float* __restrict__ x, const float* __restrict__ dt,
    const float* __restrict__ Bin, const float* __restrict__ Cin,
    const float* __restrict__ Dp, float* __restrict__ AggT,
    __half2* __restrict__ AggS, __half2* __restrict__ PreS,
    int* __restrict__ Flags, float* __restrict__ y, float A0,
    const float (&AnL)[kN], int* sflags) {
  constexpr int LC = kL / C;  // 16
  const int bid = blockIdx.x;
  const int seq = bid & (kNSEQ - 1);
  const int c = bid >> 3;
  const int b = seq >> 2;
  const int dblk = seq & 3;
  const int tid = threadIdx.x;
  const int d = dblk * kTPB + tid;
  const int t0 = c * LC;

  const float* xp = x + ((size_t)b * kL + t0) * kD + d;
  const float* dp = dt + ((size_t)b * kL + t0) * kD + d;
  const float* bp = Bin + ((size_t)b * kL + t0) * kN;
  const float* cp = Cin + ((size_t)b * kL + t0) * kN;

  float dtv[LC], xv[LC];
#pragma unroll
  for (int tt = 0; tt < LC; ++tt) {
    dtv[tt] = dp[(size_t)tt * kD];
    xv[tt] = xp[(size_t)tt * kD];
  }

  // ---- local chunk scan from zero state ----
  float s[kN];
#pragma unroll
  for (int n = 0; n < kN; ++n) s[n] = 0.f;
  float sdt = 0.f;
#pragma unroll
  for (int tt = 0; tt < LC; ++tt) {
    sdt += dtv[tt];
    const float dtx = dtv[tt] * xv[tt];
    float a[kN];
    make_pows<FAST>(dtv[tt], A0, AnL, a);
#pragma unroll
    for (int n = 0; n < kN; ++n)
      s[n] = fmaf(a[n], s[n], dtx * bp[tt * kN + n]);  // bp: scalar load
  }

  // ---- publish aggregate ----
  if (c > 0) {
    AggT[(size_t)bid * kTPB + tid] = sdt;
#pragma unroll
    for (int q = 0; q < kNH; ++q)
      AggS[((size_t)bid * kNH + q) * kTPB + tid] =
          __float22half2_rn(make_float2(s[2 * q], s[2 * q + 1]));
    __threadfence();
    __syncthreads();
    if (tid == 0)
      __hip_atomic_store(&Flags[bid], 1, __ATOMIC_RELEASE,
                         __HIP_MEMORY_SCOPE_AGENT);
  }

  // ---- windowed lookback -> s_init (si) ----
  float si[kN];
#pragma unroll
  for (int n = 0; n < kN; ++n) si[n] = 0.f;
  if (c > 0) {
    float acc_t = 0.f;
    int p = c - 1;
    while (p >= 0) {
      __syncthreads();
      if (tid < kW) {
        const int idx = p - tid;
        sflags[tid] =
            (idx >= 0)
                ? __hip_atomic_load(&Flags[idx * kNSEQ + seq], __ATOMIC_RELAXED,
                                    __HIP_MEMORY_SCOPE_AGENT)
                : 0;
      }
      __syncthreads();
      int run = 0, typ = 1;
      for (int w = 0; w < kW; ++w) {
        if (p - w < 0) break;
        const int f = sflags[w];
        if (f == 0) break;
        ++run;
        if (f == 2) {
          typ = 2;
          break;
        }
      }
      if (run == 0) {
        __builtin_amdgcn_s_sleep(2);
        continue;
      }
      __threadfence();  // acquire before payload reads
      for (int w = 0; w < run; ++w) {
        const int pbid = (p - w) * kNSEQ + seq;
        const bool pre = (typ == 2) && (w == run - 1);
        float pw[kN];
        make_pows<FAST>(acc_t, A0, AnL, pw);
        const __half2* src = pre ? PreS : AggS;
        float ps[kN];
#pragma unroll
        for (int q = 0; q < kNH; ++q) {
          const float2 v =
              __half22float2(src[((size_t)pbid * kNH + q) * kTPB + tid]);
          ps[2 * q] = v.x;
          ps[2 * q + 1] = v.y;
        }
#pragma unroll
        for (int n = 0; n < kN; ++n) si[n] = fmaf(pw[n], ps[n], si[n]);
        if (!pre) acc_t += AggT[(size_t)pbid * kTPB + tid];
      }
      if (typ == 2) break;
      p -= run;
    }
  }

  // ---- publish inclusive prefix (unblocks successors before replay) ----
  if (c < C - 1) {
    float pw[kN];
    make_pows<FAST>(sdt, A0, AnL, pw);
#pragma unroll
    for (int q = 0; q < kNH; ++q)
      PreS[((size_t)bid * kNH + q) * kTPB + tid] = __float22half2_rn(
          make_float2(fmaf(pw[2 * q], si[2 * q], s[2 * q]),
                      fmaf(pw[2 * q + 1], si[2 * q + 1], s[2 * q + 1])));
    __threadfence();
    __syncthreads();
    if (tid == 0)
      __hip_atomic_store(&Flags[bid], 2, __ATOMIC_RELEASE,
                         __HIP_MEMORY_SCOPE_AGENT);
  }

  // ---- replay from registers with true init, fused epilogue ----
  const float Dv = Dp[d];
  float* yp = y + ((size_t)b * kL + t0) * kD + d;
#pragma unroll
  for (int tt = 0; tt < LC; ++tt) {
    const float dtx = dtv[tt] * xv[tt];
    float a[kN];
    make_pows<FAST>(dtv[tt], A0, AnL, a);
    float acc = 0.f;
#pragma unroll
    for (int n = 0; n < kN; ++n) {
      si[n] = fmaf(a[n], si[n], dtx * bp[tt * kN + n]);
      acc = fmaf(si[n], cp[tt * kN + n], acc);
    }
    __builtin_nontemporal_store(fmaf(xv[tt], Dv, acc), yp + (size_t)tt * kD);
  }
}

template <int C>
__global__ __launch_bounds__(kTPB, 4) void ssm_single(
    const float* __restrict__ x, const float* __restrict__ dt,
    const float* __restrict__ Bin, const float* __restrict__ Cin,
    const float* __restrict__ Alog, const float* __restrict__ Dp,
    float* __restrict__ AggT, __half2* __restrict__ AggS,
    __half2* __restrict__ PreS, int* __restrict__ Flags,
    float* __restrict__ y) {
  __shared__ int sflags[kW];
  __shared__ int sfast;
  const int tid = threadIdx.x;
  const int seq = blockIdx.x & (kNSEQ - 1);
  const int dblk = seq & 3;
  const int d = dblk * kTPB + tid;
  const float* al = Alog + (size_t)d * kN;

  if (tid == 0) sfast = 1;
  __syncthreads();
  const bool fw = fast_check(al);
  if ((tid & 63) == 0 && !fw) atomicAnd(&sfast, 0);
  __syncthreads();
  const bool fast = (sfast != 0);  // block-uniform (syncs inside body)

  if (fast) {
    float dummy[kN] = {};
    const float A0 = -__expf(al[0]) * kLog2e;
    ssm_body<C, true>(x, dt, Bin, Cin, Dp, AggT, AggS, PreS, Flags, y, A0,
                      dummy, sflags);
  } else {
    float AnL[kN];
#pragma unroll
    for (int n = 0; n < kN; ++n) AnL[n] = -__expf(al[n]) * kLog2e;
    ssm_body<C, false>(x, dt, Bin, Cin, Dp, AggT, AggS, PreS, Flags, y, 0.f,
                       AnL, sflags);
  }
}

// ======================= fallback: proven 3-kernel path =======================
template <int C>
__global__ __launch_bounds__(kTPB) void ssm_phase1(
    const float* __restrict__ x, const float* __restrict__ dt,
    const float* __restrict__ Bin, const float* __restrict__ Alog,
    __half2* __restrict__ WSH, float* __restrict__ SDT) {
  constexpr int LC = kL / C;
  const int bid = blockIdx.x;
  const int c = bid % C;
  const int r = bid / C;
  const int dblk = r % kNDBLK;
  const int b = r / kNDBLK;
  const int d = dblk * kTPB + threadIdx.x;
  const int t0 = c * LC;

  const float* al = Alog + (size_t)d * kN;
  const bool fast = fast_check(al);

  float s[kN];
#pragma unroll
  for (int n = 0; n < kN; ++n) s[n] = 0.f;
  float sdt = 0.f;

  const float* xp = x + ((size_t)b * kL + t0) * kD + d;
  const float* dp = dt + ((size_t)b * kL + t0) * kD + d;
  const float* bp = Bin + ((size_t)b * kL + t0) * kN;

  if (fast) {
    const float A0 = -__expf(al[0]) * kLog2e;
#pragma unroll
    for (int tt = 0; tt < LC; ++tt) {
      const float dtv = dp[(size_t)tt * kD];
      const float xvv = xp[(size_t)tt * kD];
      sdt += dtv;
      const float dtx = dtv * xvv;
      float a[kN];
      build_pows(ex2(dtv * A0), a);
#pragma unroll
      for (int n = 0; n < kN; ++n)
        s[n] = fmaf(a[n], s[n], dtx * bp[tt * kN + n]);
    }
  } else {
    float AnL[kN];
#pragma unroll
    for (int n = 0; n < kN; ++n) AnL[n] = -__expf(al[n]) * kLog2e;
#pragma unroll 2
    for (int tt = 0; tt < LC; ++tt) {
      const float dtv = dp[(size_t)tt * kD];
      const float xvv = xp[(size_t)tt * kD];
      sdt += dtv;
      const float dtx = dtv * xvv;
#pragma unroll
      for (int n = 0; n < kN; ++n)
        s[n] = fmaf(ex2(dtv * AnL[n]), s[n], dtx * bp[tt * kN + n]);
    }
  }

  const size_t bd = (size_t)b * kD + d;
  const size_t base = (size_t)c * kNH * kBD + bd;
#pragma unroll
  for (int q = 0; q < kNH; ++q)
    WSH[base + (size_t)q * kBD] =
        __float22half2_rn(make_float2(s[2 * q], s[2 * q + 1]));
  SDT[(size_t)c * kBD + bd] = sdt;
}

template <int C>
__global__ __launch_bounds__(128) void ssm_phase2(
    const __half2* __restrict__ WSH, const float* __restrict__ SDT,
    const float* __restrict__ Alog, __half2* __restrict__ WIH) {
  const int j = blockIdx.x * 128 + threadIdx.x;
  const int q = j >> 11;
  const int bd = j & (kBD - 1);
  const int d = bd & (kD - 1);
  const float An0 = -__expf(Alog[(size_t)d * kN + 2 * q]) * kLog2e;
  const float An1 = -__expf(Alog[(size_t)d * kN + 2 * q + 1]) * kLog2e;
  float c0 = 0.f, c1 = 0.f;
#pragma unroll 8
  for (int c = 0; c < C; ++c) {
    const float sdt = SDT[(size_t)c * kBD + bd];
    const size_t idx = ((size_t)c * kNH + q) * kBD + bd;
    WIH[idx] = __float22half2_rn(make_float2(c0, c1));
    const float2 sf = __half22float2(WSH[idx]);
    c0 = fmaf(ex2(An0 * sdt), c0, sf.x);
    c1 = fmaf(ex2(An1 * sdt), c1, sf.y);
  }
}

template <int C>
__global__ __launch_bounds__(kTPB) void ssm_phase3(
    const float* __restrict__ x, const float* __restrict__ dt,
    const float* __restrict__ Bin, const float* __restrict__ Cin,
    const float* __restrict__ Alog, const float* __restrict__ Dp,
    const __half2* __restrict__ WIH, float* __restrict__ y) {
  constexpr int LC = kL / C;
  const int bid = blockIdx.x;
  const int c = bid % C;
  const int r = bid / C;
  const int dblk = r % kNDBLK;
  const int b = r / kNDBLK;
  const int d = dblk * kTPB + threadIdx.x;
  const int t0 = c * LC;

  const float* al = Alog + (size_t)d * kN;
  const bool fast = fast_check(al);

  float s[kN];
  const size_t bd = (size_t)b * kD + d;
  {
    const size_t base = (size_t)c * kNH * kBD + bd;
#pragma unroll
    for (int q = 0; q < kNH; ++q) {
      const float2 v = __half22float2(WIH[base + (size_t)q * kBD]);
      s[2 * q] = v.x;
      s[2 * q + 1] = v.y;
    }
  }

  const float Dv = Dp[d];
  const float* xp = x + ((size_t)b * kL + t0) * kD + d;
  const float* dp = dt + ((size_t)b * kL + t0) * kD + d;
  const float* bp = Bin + ((size_t)b * kL + t0) * kN;
  const float* cp = Cin + ((size_t)b * kL + t0) * kN;
  float* yp = y + ((size_t)b * kL + t0) * kD + d;

  if (fast) {
    const float A0 = -__expf(al[0]) * kLog2e;
#pragma unroll
    for (int tt = 0; tt < LC; ++tt) {
      const float dtv = dp[(size_t)tt * kD];
      const float xvv = xp[(size_t)tt * kD];
      const float dtx = dtv * xvv;
      float a[kN];
      build_pows(ex2(dtv * A0), a);
      float acc = 0.f;
#pragma unroll
      for (int n = 0; n < kN; ++n) {
        s[n] = fmaf(a[n], s[n], dtx * bp[tt * kN + n]);
        acc = fmaf(s[n], cp[tt * kN + n], acc);
      }
      __builtin_nontemporal_store(fmaf(xvv, Dv, acc), yp + (size_t)tt * kD);
    }
  } else {
    float AnL[kN];
#pragma unroll
    for (int n = 0; n < kN; ++n) AnL[n] = -__expf(al[n]) * kLog2e;
#pragma unroll 2
    for (int tt = 0; tt < LC; ++tt) {
      const float dtv = dp[(size_t)tt * kD];
      const float xvv = xp[(size_t)tt * kD];
      const float dtx = dtv * xvv;
      float acc = 0.f;
#pragma unroll
      for (int n = 0; n < kN; ++n) {
        s[n] = fmaf(ex2(dtv * AnL[n]), s[n], dtx * bp[tt * kN + n]);
        acc = fmaf(s[n], cp[tt * kN + n], acc);
      }
      __builtin_nontemporal_store(fmaf(xvv, Dv, acc), yp + (size_t)tt * kD);
    }
  }
}

__global__ __launch_bounds__(256) void ssm_seq(
    const float* __restrict__ x, const float* __restrict__ dt,
    const float* __restrict__ Bin, const float* __restrict__ Cin,
    const float* __restrict__ Alog, const float* __restrict__ Dp,
    float* __restrict__ y) {
  const int gid = blockIdx.x * 256 + threadIdx.x;
  if (gid >= kB * kD) return;
  const int b = gid / kD;
  const int d = gid % kD;

  float AnL[kN];
  const float* al = Alog + (size_t)d * kN;
#pragma unroll
  for (int n = 0; n < kN; ++n) AnL[n] = -__expf(al[n]) * kLog2e;

  float s[kN];
#pragma unroll
  for (int n = 0; n < kN; ++n) s[n] = 0.f;
  const float Dv = Dp[d];

  const float* xp = x + (size_t)b * kL * kD + d;
  const float* dp = dt + (size_t)b * kL * kD + d;
  const float* bp = Bin + (size_t)b * kL * kN;
  const float* cp = Cin + (size_t)b * kL * kN;
  float* yp = y + (size_t)b * kL * kD + d;

  for (int t = 0; t < kL; ++t) {
    const float dtv = dp[(size_t)t * kD];
    const float xvv = xp[(size_t)t * kD];
    const float dtx = dtv * xvv;
    float acc = 0.f;
#pragma unroll
    for (int n = 0; n < kN; ++n) {
      const float a = ex2(dtv * AnL[n]);
      s[n] = fmaf(a, s[n], dtx * bp[t * kN + n]);
      acc = fmaf(s[n], cp[t * kN + n], acc);
    }
    yp[(size_t)t * kD] = fmaf(xvv, Dv, acc);
  }
}

template <int C>
void launch_chunked(const float* x, const float* dtp, const float* Bin,
                    const float* Cin, const float* Alog, const float* Dp,
                    float* y, void* ws, hipStream_t stream) {
  __half2* WSH = reinterpret_cast<__half2*>(ws);
  __half2* WIH = WSH + (size_t)C * kNH * kBD;
  float* SDT = reinterpret_cast<float*>(WIH + (size_t)C * kNH * kBD);
  const int g = C * kB * kNDBLK;
  ssm_phase1<C><<<g, kTPB, 0, stream>>>(x, dtp, Bin, Alog, WSH, SDT);
  ssm_phase2<C><<<kBDN / 2 / 128, 128, 0, stream>>>(WSH, SDT, Alog, WIH);
  ssm_phase3<C><<<g, kTPB, 0, stream>>>(x, dtp, Bin, Cin, Alog, Dp, WIH, y);
}

}  // namespace

extern "C" void kernel_launch(void* const* d_in, const int* in_sizes, int n_in,
                              void* d_out, int out_size, void* d_ws, size_t ws_size,
                              hipStream_t stream) {
  const float* x    = (const float*)d_in[0];
  const float* dtp  = (const float*)d_in[1];
  const float* Bin  = (const float*)d_in[2];
  const float* Cin  = (const float*)d_in[3];
  const float* Alog = (const float*)d_in[4];
  const float* Dp   = (const float*)d_in[5];
  float* y = (float*)d_out;

  constexpr int C = 128;
  constexpr int nblk = C * kNSEQ;  // 1024
  // ws layout (4 KB-aligned): Flags | AggT | AggS | PreS
  const size_t offFlags = 0;
  const size_t offAggT = 4096;
  const size_t offAggS = offAggT + (size_t)nblk * kTPB * sizeof(float);
  const size_t offPreS =
      offAggS + (size_t)nblk * kNH * kTPB * sizeof(__half2);
  const size_t needSingle =
      offPreS + (size_t)nblk * kNH * kTPB * sizeof(__half2);

  auto need3 = [](int Cc) {
    return (size_t)Cc * kNH * kBD * 2 * sizeof(__half2) +
           (size_t)Cc * kBD * sizeof(float);
  };

  if (ws_size >= needSingle) {
    char* base = (char*)d_ws;
    int* Flags = (int*)(base + offFlags);
    float* AggT = (float*)(base + offAggT);
    __half2* AggS = (__half2*)(base + offAggS);
    __half2* PreS = (__half2*)(base + offPreS);
    hipMemsetAsync(Flags, 0, (size_t)nblk * sizeof(int), stream);
    ssm_single<C><<<nblk, kTPB, 0, stream>>>(x, dtp, Bin, Cin, Alog, Dp, AggT,
                                             AggS, PreS, Flags, y);
  } else if (ws_size >= need3(128)) {
    launch_chunked<128>(x, dtp, Bin, Cin, Alog, Dp, y, d_ws, stream);
  } else if (ws_size >= need3(64)) {
    launch_chunked<64>(x, dtp, Bin, Cin, Alog, Dp, y, d_ws, stream);
  } else {
    ssm_seq<<<(kB * kD + 255) / 256, 256, 0, stream>>>(x, dtp, Bin, Cin, Alog,
                                                       Dp, y);
  }
}

// Round 9
// 60.629 us; speedup vs baseline: 15.3272x; 15.3272x over previous
//
#include <hip/hip_runtime.h>
#include <hip/hip_bf16.h>
#include <hip/hip_fp16.h>

namespace {

constexpr int kB = 2;
constexpr int kL = 2048;
constexpr int kD = 1024;
constexpr int kN = 16;
constexpr int kNH = kN / 2;                 // half2 pairs
constexpr int kTPB = 256;
constexpr int kNDBLK = kD / kTPB;           // 4 blocks cover D
constexpr int kNSEQ = kB * kNDBLK;          // 8 independent (b, dblk) sequences
constexpr int kBD = kB * kD;                // 2048
constexpr int kBDN = kBD * kN;              // 32768
constexpr int kC = 128;                     // chunks (single-kernel path)
constexpr int kLC = kL / kC;                // 16
constexpr float kLog2e = 1.4426950408889634f;

// ln(n+1) for n=0..15 (log-domain fast check: no transcendentals)
__device__ __constant__ float kLn[kN] = {
    0.0f,        0.69314718f, 1.09861229f, 1.38629436f,
    1.60943791f, 1.79175947f, 1.94591015f, 2.07944154f,
    2.19722458f, 2.30258509f, 2.39789527f, 2.48490665f,
    2.56494936f, 2.63905733f, 2.70805020f, 2.77258872f};

__device__ __forceinline__ float ex2(float v) {
  return __builtin_amdgcn_exp2f(v);
}

// a[n] = e1^(n+1), log-depth (4 squares + 11 muls)
__device__ __forceinline__ void build_pows(float e1, float* a) {
  const float p2 = e1 * e1;
  const float p4 = p2 * p2;
  const float p8 = p4 * p4;
  a[0] = e1;      a[1] = p2;      a[2] = p2 * e1;  a[3] = p4;
  a[4] = p4 * e1; a[5] = p4 * p2; a[6] = p4 * a[2]; a[7] = p8;
  a[8] = p8 * e1; a[9] = p8 * p2; a[10] = p8 * a[2]; a[11] = p8 * p4;
  a[12] = p8 * a[4]; a[13] = p8 * a[5]; a[14] = p8 * a[6]; a[15] = p8 * p8;
}

__device__ __forceinline__ bool fast_check(const float* __restrict__ al) {
  const float a0 = al[0];
  bool f = true;
#pragma unroll
  for (int n = 1; n < kN; ++n)
    f = f && (fabsf(al[n] - a0 - kLn[n]) <= 1e-3f);
  return __all(f);
}

template <bool FAST>
__device__ __forceinline__ void make_pows(float t, float A0,
                                          const float (&AnL)[kN], float* a) {
  if (FAST) {
    build_pows(ex2(t * A0), a);
  } else {
#pragma unroll
    for (int n = 0; n < kN; ++n) a[n] = ex2(t * AnL[n]);
  }
}

// =============== single-kernel, depth-1 sync (publish -> scan -> flag) ======
// bid = c*kNSEQ + seq.  Aggregates laid out per sequence:
//   SDT[seq][c][tid] f32, WSH/WIH[seq][c][q][tid] half2  (tid-fastest, coalesced)
// Cnt[seq]: publish counter; last publisher scans all C chunks, writes WIH,
// sets Flag[seq]. Everyone spins on Flag[seq] only (single hop).

template <bool FAST>
__device__ __forceinline__ void spin_body(
    const float* __restrict__ x, const float* __restrict__ dt,
    const float* __restrict__ Bin, const float* __restrict__ Cin,
    const float* __restrict__ Dp, float* __restrict__ SDT,
    __half2* __restrict__ WSH, __half2* __restrict__ WIH,
    int* __restrict__ Cnt, int* __restrict__ Flag, float* __restrict__ y,
    float A0, const float (&AnL)[kN], int* __restrict__ sh) {
  constexpr int C = kC, LC = kLC;
  const int bid = blockIdx.x;
  const int seq = bid & (kNSEQ - 1);
  const int c = bid >> 3;
  const int b = seq >> 2;
  const int dblk = seq & 3;
  const int tid = threadIdx.x;
  const int d = dblk * kTPB + tid;
  const int t0 = c * LC;

  const float* xp = x + ((size_t)b * kL + t0) * kD + d;
  const float* dp = dt + ((size_t)b * kL + t0) * kD + d;
  const float* bp = Bin + ((size_t)b * kL + t0) * kN;
  const float* cp = Cin + ((size_t)b * kL + t0) * kN;

  // x/dt live in registers across the whole kernel (no second read)
  float dtv[LC], xv[LC];
#pragma unroll
  for (int tt = 0; tt < LC; ++tt) {
    dtv[tt] = dp[(size_t)tt * kD];
    xv[tt] = xp[(size_t)tt * kD];
  }

  // ---- local chunk scan from zero state ----
  float s[kN];
#pragma unroll
  for (int n = 0; n < kN; ++n) s[n] = 0.f;
  float sdt = 0.f;
#pragma unroll
  for (int tt = 0; tt < LC; ++tt) {
    sdt += dtv[tt];
    const float dtx = dtv[tt] * xv[tt];
    float a[kN];
    make_pows<FAST>(dtv[tt], A0, AnL, a);
#pragma unroll
    for (int n = 0; n < kN; ++n)
      s[n] = fmaf(a[n], s[n], dtx * bp[tt * kN + n]);  // bp: scalar load
  }

  // ---- publish aggregate ----
  const size_t ab = (size_t)seq * C + c;
  SDT[ab * kTPB + tid] = sdt;
#pragma unroll
  for (int q = 0; q < kNH; ++q)
    WSH[(ab * kNH + q) * kTPB + tid] =
        __float22half2_rn(make_float2(s[2 * q], s[2 * q + 1]));
  __threadfence();
  __syncthreads();
  if (tid == 0) sh[0] = (atomicAdd(&Cnt[seq], 1) == C - 1) ? 1 : 0;
  __syncthreads();

  // ---- last publisher scans the whole sequence (depth-1, no chaining) ----
  if (sh[0]) {
    __threadfence();  // acquire: all publishers' fences precede our counter obs
    float carry[kN];
#pragma unroll
    for (int n = 0; n < kN; ++n) carry[n] = 0.f;
#pragma unroll 2
    for (int cc = 0; cc < C; ++cc) {
      const size_t a2 = (size_t)seq * C + cc;
#pragma unroll
      for (int q = 0; q < kNH; ++q)
        WIH[(a2 * kNH + q) * kTPB + tid] =
            __float22half2_rn(make_float2(carry[2 * q], carry[2 * q + 1]));
      const float sdtc = SDT[a2 * kTPB + tid];
      float pw[kN];
      make_pows<FAST>(sdtc, A0, AnL, pw);
#pragma unroll
      for (int q = 0; q < kNH; ++q) {
        const float2 v = __half22float2(WSH[(a2 * kNH + q) * kTPB + tid]);
        carry[2 * q] = fmaf(pw[2 * q], carry[2 * q], v.x);
        carry[2 * q + 1] = fmaf(pw[2 * q + 1], carry[2 * q + 1], v.y);
      }
    }
    __threadfence();
    __syncthreads();
    if (tid == 0)
      __hip_atomic_store(&Flag[seq], 1, __ATOMIC_RELEASE,
                         __HIP_MEMORY_SCOPE_AGENT);
  }

  // ---- wait for sequence prefix (single flag, single hop) ----
  if (tid == 0) {
    while (__hip_atomic_load(&Flag[seq], __ATOMIC_ACQUIRE,
                             __HIP_MEMORY_SCOPE_AGENT) == 0)
      __builtin_amdgcn_s_sleep(2);
  }
  __syncthreads();
  __threadfence();

  // ---- replay from registers with true init, fused epilogue ----
  float si[kN];
#pragma unroll
  for (int q = 0; q < kNH; ++q) {
    const float2 v = __half22float2(WIH[(ab * kNH + q) * kTPB + tid]);
    si[2 * q] = v.x;
    si[2 * q + 1] = v.y;
  }
  const float Dv = Dp[d];
  float* yp = y + ((size_t)b * kL + t0) * kD + d;
#pragma unroll
  for (int tt = 0; tt < LC; ++tt) {
    const float dtx = dtv[tt] * xv[tt];
    float a[kN];
    make_pows<FAST>(dtv[tt], A0, AnL, a);
    float acc = 0.f;
#pragma unroll
    for (int n = 0; n < kN; ++n) {
      si[n] = fmaf(a[n], si[n], dtx * bp[tt * kN + n]);
      acc = fmaf(si[n], cp[tt * kN + n], acc);
    }
    __builtin_nontemporal_store(fmaf(xv[tt], Dv, acc), yp + (size_t)tt * kD);
  }
}

__global__ __launch_bounds__(kTPB, 4) void ssm_spin(
    const float* __restrict__ x, const float* __restrict__ dt,
    const float* __restrict__ Bin, const float* __restrict__ Cin,
    const float* __restrict__ Alog, const float* __restrict__ Dp,
    float* __restrict__ SDT, __half2* __restrict__ WSH,
    __half2* __restrict__ WIH, int* __restrict__ Cnt, int* __restrict__ Flag,
    float* __restrict__ y) {
  __shared__ int sh[1];
  __shared__ int sfast;
  const int tid = threadIdx.x;
  const int seq = blockIdx.x & (kNSEQ - 1);
  const int dblk = seq & 3;
  const int d = dblk * kTPB + tid;
  const float* al = Alog + (size_t)d * kN;

  if (tid == 0) sfast = 1;
  __syncthreads();
  const bool fw = fast_check(al);
  if ((tid & 63) == 0 && !fw) atomicAnd(&sfast, 0);
  __syncthreads();
  const bool fast = (sfast != 0);

  if (fast) {
    float dummy[kN] = {};
    const float A0 = -__expf(al[0]) * kLog2e;
    spin_body<true>(x, dt, Bin, Cin, Dp, SDT, WSH, WIH, Cnt, Flag, y, A0,
                    dummy, sh);
  } else {
    float AnL[kN];
#pragma unroll
    for (int n = 0; n < kN; ++n) AnL[n] = -__expf(al[n]) * kLog2e;
    spin_body<false>(x, dt, Bin, Cin, Dp, SDT, WSH, WIH, Cnt, Flag, y, 0.f,
                     AnL, sh);
  }
}

// ======================= fallback: proven 3-kernel path (R6) ================
template <int C>
__global__ __launch_bounds__(kTPB) void ssm_phase1(
    const float* __restrict__ x, const float* __restrict__ dt,
    const float* __restrict__ Bin, const float* __restrict__ Alog,
    __half2* __restrict__ WSH, float* __restrict__ SDT) {
  constexpr int LC = kL / C;
  const int bid = blockIdx.x;
  const int c = bid % C;
  const int r = bid / C;
  const int dblk = r % kNDBLK;
  const int b = r / kNDBLK;
  const int d = dblk * kTPB + threadIdx.x;
  const int t0 = c * LC;

  const float* al = Alog + (size_t)d * kN;
  const bool fast = fast_check(al);

  float s[kN];
#pragma unroll
  for (int n = 0; n < kN; ++n) s[n] = 0.f;
  float sdt = 0.f;

  const float* xp = x + ((size_t)b * kL + t0) * kD + d;
  const float* dp = dt + ((size_t)b * kL + t0) * kD + d;
  const float* bp = Bin + ((size_t)b * kL + t0) * kN;

  if (fast) {
    const float A0 = -__expf(al[0]) * kLog2e;
#pragma unroll
    for (int tt = 0; tt < LC; ++tt) {
      const float dtv = dp[(size_t)tt * kD];
      const float xvv = xp[(size_t)tt * kD];
      sdt += dtv;
      const float dtx = dtv * xvv;
      float a[kN];
      build_pows(ex2(dtv * A0), a);
#pragma unroll
      for (int n = 0; n < kN; ++n)
        s[n] = fmaf(a[n], s[n], dtx * bp[tt * kN + n]);
    }
  } else {
    float AnL[kN];
#pragma unroll
    for (int n = 0; n < kN; ++n) AnL[n] = -__expf(al[n]) * kLog2e;
#pragma unroll 2
    for (int tt = 0; tt < LC; ++tt) {
      const float dtv = dp[(size_t)tt * kD];
      const float xvv = xp[(size_t)tt * kD];
      sdt += dtv;
      const float dtx = dtv * xvv;
#pragma unroll
      for (int n = 0; n < kN; ++n)
        s[n] = fmaf(ex2(dtv * AnL[n]), s[n], dtx * bp[tt * kN + n]);
    }
  }

  const size_t bd = (size_t)b * kD + d;
  const size_t base = (size_t)c * kNH * kBD + bd;
#pragma unroll
  for (int q = 0; q < kNH; ++q)
    WSH[base + (size_t)q * kBD] =
        __float22half2_rn(make_float2(s[2 * q], s[2 * q + 1]));
  SDT[(size_t)c * kBD + bd] = sdt;
}

template <int C>
__global__ __launch_bounds__(128) void ssm_phase2(
    const __half2* __restrict__ WSH, const float* __restrict__ SDT,
    const float* __restrict__ Alog, __half2* __restrict__ WIH) {
  const int j = blockIdx.x * 128 + threadIdx.x;
  const int q = j >> 11;
  const int bd = j & (kBD - 1);
  const int d = bd & (kD - 1);
  const float An0 = -__expf(Alog[(size_t)d * kN + 2 * q]) * kLog2e;
  const float An1 = -__expf(Alog[(size_t)d * kN + 2 * q + 1]) * kLog2e;
  float c0 = 0.f, c1 = 0.f;
#pragma unroll 8
  for (int c = 0; c < C; ++c) {
    const float sdt = SDT[(size_t)c * kBD + bd];
    const size_t idx = ((size_t)c * kNH + q) * kBD + bd;
    WIH[idx] = __float22half2_rn(make_float2(c0, c1));
    const float2 sf = __half22float2(WSH[idx]);
    c0 = fmaf(ex2(An0 * sdt), c0, sf.x);
    c1 = fmaf(ex2(An1 * sdt), c1, sf.y);
  }
}

template <int C>
__global__ __launch_bounds__(kTPB) void ssm_phase3(
    const float* __restrict__ x, const float* __restrict__ dt,
    const float* __restrict__ Bin, const float* __restrict__ Cin,
    const float* __restrict__ Alog, const float* __restrict__ Dp,
    const __half2* __restrict__ WIH, float* __restrict__ y) {
  constexpr int LC = kL / C;
  const int bid = blockIdx.x;
  const int c = bid % C;
  const int r = bid / C;
  const int dblk = r % kNDBLK;
  const int b = r / kNDBLK;
  const int d = dblk * kTPB + threadIdx.x;
  const int t0 = c * LC;

  const float* al = Alog + (size_t)d * kN;
  const bool fast = fast_check(al);

  float s[kN];
  const size_t bd = (size_t)b * kD + d;
  {
    const size_t base = (size_t)c * kNH * kBD + bd;
#pragma unroll
    for (int q = 0; q < kNH; ++q) {
      const float2 v = __half22float2(WIH[base + (size_t)q * kBD]);
      s[2 * q] = v.x;
      s[2 * q + 1] = v.y;
    }
  }

  const float Dv = Dp[d];
  const float* xp = x + ((size_t)b * kL + t0) * kD + d;
  const float* dp = dt + ((size_t)b * kL + t0) * kD + d;
  const float* bp = Bin + ((size_t)b * kL + t0) * kN;
  const float* cp = Cin + ((size_t)b * kL + t0) * kN;
  float* yp = y + ((size_t)b * kL + t0) * kD + d;

  if (fast) {
    const float A0 = -__expf(al[0]) * kLog2e;
#pragma unroll
    for (int tt = 0; tt < LC; ++tt) {
      const float dtv = dp[(size_t)tt * kD];
      const float xvv = xp[(size_t)tt * kD];
      const float dtx = dtv * xvv;
      float a[kN];
      build_pows(ex2(dtv * A0), a);
      float acc = 0.f;
#pragma unroll
      for (int n = 0; n < kN; ++n) {
        s[n] = fmaf(a[n], s[n], dtx * bp[tt * kN + n]);
        acc = fmaf(s[n], cp[tt * kN + n], acc);
      }
      __builtin_nontemporal_store(fmaf(xvv, Dv, acc), yp + (size_t)tt * kD);
    }
  } else {
    float AnL[kN];
#pragma unroll
    for (int n = 0; n < kN; ++n) AnL[n] = -__expf(al[n]) * kLog2e;
#pragma unroll 2
    for (int tt = 0; tt < LC; ++tt) {
      const float dtv = dp[(size_t)tt * kD];
      const float xvv = xp[(size_t)tt * kD];
      const float dtx = dtv * xvv;
      float acc = 0.f;
#pragma unroll
      for (int n = 0; n < kN; ++n) {
        s[n] = fmaf(ex2(dtv * AnL[n]), s[n], dtx * bp[tt * kN + n]);
        acc = fmaf(s[n], cp[tt * kN + n], acc);
      }
      __builtin_nontemporal_store(fmaf(xvv, Dv, acc), yp + (size_t)tt * kD);
    }
  }
}

__global__ __launch_bounds__(256) void ssm_seq(
    const float* __restrict__ x, const float* __restrict__ dt,
    const float* __restrict__ Bin, const float* __restrict__ Cin,
    const float* __restrict__ Alog, const float* __restrict__ Dp,
    float* __restrict__ y) {
  const int gid = blockIdx.x * 256 + threadIdx.x;
  if (gid >= kB * kD) return;
  const int b = gid / kD;
  const int d = gid % kD;

  float AnL[kN];
  const float* al = Alog + (size_t)d * kN;
#pragma unroll
  for (int n = 0; n < kN; ++n) AnL[n] = -__expf(al[n]) * kLog2e;

  float s[kN];
#pragma unroll
  for (int n = 0; n < kN; ++n) s[n] = 0.f;
  const float Dv = Dp[d];

  const float* xp = x + (size_t)b * kL * kD + d;
  const float* dp = dt + (size_t)b * kL * kD + d;
  const float* bp = Bin + (size_t)b * kL * kN;
  const float* cp = Cin + (size_t)b * kL * kN;
  float* yp = y + (size_t)b * kL * kD + d;

  for (int t = 0; t < kL; ++t) {
    const float dtv = dp[(size_t)t * kD];
    const float xvv = xp[(size_t)t * kD];
    const float dtx = dtv * xvv;
    float acc = 0.f;
#pragma unroll
    for (int n = 0; n < kN; ++n) {
      const float a = ex2(dtv * AnL[n]);
      s[n] = fmaf(a, s[n], dtx * bp[t * kN + n]);
      acc = fmaf(s[n], cp[t * kN + n], acc);
    }
    yp[(size_t)t * kD] = fmaf(xvv, Dv, acc);
  }
}

template <int C>
void launch_chunked(const float* x, const float* dtp, const float* Bin,
                    const float* Cin, const float* Alog, const float* Dp,
                    float* y, void* ws, hipStream_t stream) {
  __half2* WSH = reinterpret_cast<__half2*>(ws);
  __half2* WIH = WSH + (size_t)C * kNH * kBD;
  float* SDT = reinterpret_cast<float*>(WIH + (size_t)C * kNH * kBD);
  const int g = C * kB * kNDBLK;
  ssm_phase1<C><<<g, kTPB, 0, stream>>>(x, dtp, Bin, Alog, WSH, SDT);
  ssm_phase2<C><<<kBDN / 2 / 128, 128, 0, stream>>>(WSH, SDT, Alog, WIH);
  ssm_phase3<C><<<g, kTPB, 0, stream>>>(x, dtp, Bin, Cin, Alog, Dp, WIH, y);
}

}  // namespace

extern "C" void kernel_launch(void* const* d_in, const int* in_sizes, int n_in,
                              void* d_out, int out_size, void* d_ws, size_t ws_size,
                              hipStream_t stream) {
  const float* x    = (const float*)d_in[0];
  const float* dtp  = (const float*)d_in[1];
  const float* Bin  = (const float*)d_in[2];
  const float* Cin  = (const float*)d_in[3];
  const float* Alog = (const float*)d_in[4];
  const float* Dp   = (const float*)d_in[5];
  float* y = (float*)d_out;

  constexpr int nblk = kC * kNSEQ;  // 1024
  // ws layout: [ctl 4KB: Cnt[8], Flag[8]] [SDT f32] [WSH half2] [WIH half2]
  const size_t offSDT = 4096;
  const size_t offWSH = offSDT + (size_t)kNSEQ * kC * kTPB * sizeof(float);
  const size_t offWIH =
      offWSH + (size_t)kNSEQ * kC * kNH * kTPB * sizeof(__half2);
  const size_t needSpin =
      offWIH + (size_t)kNSEQ * kC * kNH * kTPB * sizeof(__half2);

  auto need3 = [](int Cc) {
    return (size_t)Cc * kNH * kBD * 2 * sizeof(__half2) +
           (size_t)Cc * kBD * sizeof(float);
  };

  // Deadlock guard: all 1024 blocks must be co-resident (>=4 blocks/CU).
  int maxb = 0;
  const bool coresident =
      (hipOccupancyMaxActiveBlocksPerMultiprocessor(&maxb, ssm_spin, kTPB, 0) ==
       hipSuccess) &&
      (maxb >= 4);

  if (coresident && ws_size >= needSpin) {
    char* base = (char*)d_ws;
    int* Cnt = (int*)base;          // [0..7]
    int* Flag = (int*)base + 8;     // [8..15]
    float* SDT = (float*)(base + offSDT);
    __half2* WSH = (__half2*)(base + offWSH);
    __half2* WIH = (__half2*)(base + offWIH);
    hipMemsetAsync(base, 0, 64, stream);
    ssm_spin<<<nblk, kTPB, 0, stream>>>(x, dtp, Bin, Cin, Alog, Dp, SDT, WSH,
                                        WIH, Cnt, Flag, y);
  } else if (ws_size >= need3(128)) {
    launch_chunked<128>(x, dtp, Bin, Cin, Alog, Dp, y, d_ws, stream);
  } else if (ws_size >= need3(64)) {
    launch_chunked<64>(x, dtp, Bin, Cin, Alog, Dp, y, d_ws, stream);
  } else {
    ssm_seq<<<(kB * kD + 255) / 256, 256, 0, stream>>>(x, dtp, Bin, Cin, Alog,
                                                       Dp, y);
  }
}

// Round 10
// 51.930 us; speedup vs baseline: 17.8946x; 1.1675x over previous
//
#include <hip/hip_runtime.h>
#include <hip/hip_bf16.h>
#include <hip/hip_fp16.h>

namespace {

constexpr int kB = 2;
constexpr int kL = 2048;
constexpr int kD = 1024;
constexpr int kN = 16;
constexpr int kNH = kN / 2;                 // half2 pairs
constexpr int kTPB = 256;
constexpr int kNDBLK = kD / kTPB;           // 4 blocks cover D
constexpr int kBD = kB * kD;                // 2048
constexpr int kBDN = kBD * kN;              // 32768
constexpr float kLog2e = 1.4426950408889634f;

// ln(n+1) for n=0..15 (log-domain fast check: no transcendentals)
__device__ __constant__ float kLn[kN] = {
    0.0f,        0.69314718f, 1.09861229f, 1.38629436f,
    1.60943791f, 1.79175947f, 1.94591015f, 2.07944154f,
    2.19722458f, 2.30258509f, 2.39789527f, 2.48490665f,
    2.56494936f, 2.63905733f, 2.70805020f, 2.77258872f};

__device__ __forceinline__ float ex2(float v) {
  return __builtin_amdgcn_exp2f(v);
}

// a[n] = e1^(n+1), log-depth (4 squares + 11 muls)
__device__ __forceinline__ void build_pows(float e1, float* a) {
  const float p2 = e1 * e1;
  const float p4 = p2 * p2;
  const float p8 = p4 * p4;
  a[0] = e1;      a[1] = p2;      a[2] = p2 * e1;  a[3] = p4;
  a[4] = p4 * e1; a[5] = p4 * p2; a[6] = p4 * a[2]; a[7] = p8;
  a[8] = p8 * e1; a[9] = p8 * p2; a[10] = p8 * a[2]; a[11] = p8 * p4;
  a[12] = p8 * a[4]; a[13] = p8 * a[5]; a[14] = p8 * a[6]; a[15] = p8 * p8;
}

__device__ __forceinline__ bool fast_check(const float* __restrict__ al) {
  const float a0 = al[0];
  bool f = true;
#pragma unroll
  for (int n = 1; n < kN; ++n)
    f = f && (fabsf(al[n] - a0 - kLn[n]) <= 1e-3f);
  return __all(f);
}

template <bool FAST>
__device__ __forceinline__ void make_pows(float t, float A0,
                                          const float (&AnL)[kN], float* a) {
  if (FAST) {
    build_pows(ex2(t * A0), a);
  } else {
#pragma unroll
    for (int n = 0; n < kN; ++n) a[n] = ex2(t * AnL[n]);
  }
}

// ===================== 2-kernel, zero-sync chunked scan =====================
// Aggregates: WSH half2[C][kNH][kBD] (chunk-local final states),
//             SDT f32  [C][kBD]      (chunk dt-sums).
// Kernel A: local scan from zero, publish aggregates.
// Kernel B: redundantly combine aggregate prefix (c' < c) -> true init,
//           then replay chunk with fused epilogue. No atomics/spin: the
//           kernel boundary guarantees visibility.

// ---------------- Kernel A ----------------
template <int C, bool FAST>
__device__ __forceinline__ void partA_body(
    const float* __restrict__ xp, const float* __restrict__ dp,
    const float* __restrict__ bp, float A0, const float (&AnL)[kN],
    float* __restrict__ s, float& sdt) {
  constexpr int LC = kL / C;
#pragma unroll 4
  for (int tt = 0; tt < LC; ++tt) {
    const float dtv = dp[(size_t)tt * kD];
    const float xv = xp[(size_t)tt * kD];
    sdt += dtv;
    const float dtx = dtv * xv;
    float a[kN];
    make_pows<FAST>(dtv, A0, AnL, a);
#pragma unroll
    for (int n = 0; n < kN; ++n)
      s[n] = fmaf(a[n], s[n], dtx * bp[tt * kN + n]);  // bp: scalar load
  }
}

template <int C>
__global__ __launch_bounds__(kTPB) void ssm2_partA(
    const float* __restrict__ x, const float* __restrict__ dt,
    const float* __restrict__ Bin, const float* __restrict__ Alog,
    __half2* __restrict__ WSH, float* __restrict__ SDT) {
  constexpr int LC = kL / C;
  const int bid = blockIdx.x;
  const int c = bid % C;
  const int r = bid / C;
  const int dblk = r % kNDBLK;
  const int b = r / kNDBLK;
  const int tid = threadIdx.x;
  const int d = dblk * kTPB + tid;
  const int t0 = c * LC;

  const float* al = Alog + (size_t)d * kN;
  const bool fast = fast_check(al);

  const float* xp = x + ((size_t)b * kL + t0) * kD + d;
  const float* dp = dt + ((size_t)b * kL + t0) * kD + d;
  const float* bp = Bin + ((size_t)b * kL + t0) * kN;

  float s[kN];
#pragma unroll
  for (int n = 0; n < kN; ++n) s[n] = 0.f;
  float sdt = 0.f;

  if (fast) {
    float dummy[kN] = {};
    const float A0 = -__expf(al[0]) * kLog2e;
    partA_body<C, true>(xp, dp, bp, A0, dummy, s, sdt);
  } else {
    float AnL[kN];
#pragma unroll
    for (int n = 0; n < kN; ++n) AnL[n] = -__expf(al[n]) * kLog2e;
    partA_body<C, false>(xp, dp, bp, 0.f, AnL, s, sdt);
  }

  const size_t bd = (size_t)b * kD + d;
#pragma unroll
  for (int q = 0; q < kNH; ++q)
    WSH[((size_t)c * kNH + q) * kBD + bd] =
        __float22half2_rn(make_float2(s[2 * q], s[2 * q + 1]));
  SDT[(size_t)c * kBD + bd] = sdt;
}

// ---------------- Kernel B ----------------
template <int C, bool FAST>
__device__ __forceinline__ void partB_body(
    const float* __restrict__ xp, const float* __restrict__ dp,
    const float* __restrict__ bp, const float* __restrict__ cp,
    const __half2* __restrict__ WSH, const float* __restrict__ SDT,
    float* __restrict__ yp, float A0, const float (&AnL)[kN], int c,
    size_t bd, float Dv) {
  constexpr int LC = kL / C;
  // ---- redundant prefix combine over aggregates (cached in L2/L3) ----
  float si[kN];
#pragma unroll
  for (int n = 0; n < kN; ++n) si[n] = 0.f;
#pragma unroll 2
  for (int cc = 0; cc < c; ++cc) {
    const float sdtc = SDT[(size_t)cc * kBD + bd];
    float pw[kN];
    make_pows<FAST>(sdtc, A0, AnL, pw);
#pragma unroll
    for (int q = 0; q < kNH; ++q) {
      const float2 v =
          __half22float2(WSH[((size_t)cc * kNH + q) * kBD + bd]);
      si[2 * q] = fmaf(pw[2 * q], si[2 * q], v.x);
      si[2 * q + 1] = fmaf(pw[2 * q + 1], si[2 * q + 1], v.y);
    }
  }
  // ---- replay with true init, fused epilogue ----
#pragma unroll 4
  for (int tt = 0; tt < LC; ++tt) {
    const float dtv = dp[(size_t)tt * kD];
    const float xv = xp[(size_t)tt * kD];
    const float dtx = dtv * xv;
    float a[kN];
    make_pows<FAST>(dtv, A0, AnL, a);
    float acc = 0.f;
#pragma unroll
    for (int n = 0; n < kN; ++n) {
      si[n] = fmaf(a[n], si[n], dtx * bp[tt * kN + n]);
      acc = fmaf(si[n], cp[tt * kN + n], acc);
    }
    __builtin_nontemporal_store(fmaf(xv, Dv, acc), yp + (size_t)tt * kD);
  }
}

template <int C>
__global__ __launch_bounds__(kTPB) void ssm2_partB(
    const float* __restrict__ x, const float* __restrict__ dt,
    const float* __restrict__ Bin, const float* __restrict__ Cin,
    const float* __restrict__ Alog, const float* __restrict__ Dp,
    const __half2* __restrict__ WSH, const float* __restrict__ SDT,
    float* __restrict__ y) {
  constexpr int LC = kL / C;
  const int bid = blockIdx.x;
  const int c = bid % C;
  const int r = bid / C;
  const int dblk = r % kNDBLK;
  const int b = r / kNDBLK;
  const int tid = threadIdx.x;
  const int d = dblk * kTPB + tid;
  const int t0 = c * LC;

  const float* al = Alog + (size_t)d * kN;
  const bool fast = fast_check(al);

  const float* xp = x + ((size_t)b * kL + t0) * kD + d;
  const float* dp = dt + ((size_t)b * kL + t0) * kD + d;
  const float* bp = Bin + ((size_t)b * kL + t0) * kN;
  const float* cp = Cin + ((size_t)b * kL + t0) * kN;
  float* yp = y + ((size_t)b * kL + t0) * kD + d;
  const size_t bd = (size_t)b * kD + d;
  const float Dv = Dp[d];

  if (fast) {
    float dummy[kN] = {};
    const float A0 = -__expf(al[0]) * kLog2e;
    partB_body<C, true>(xp, dp, bp, cp, WSH, SDT, yp, A0, dummy, c, bd, Dv);
  } else {
    float AnL[kN];
#pragma unroll
    for (int n = 0; n < kN; ++n) AnL[n] = -__expf(al[n]) * kLog2e;
    partB_body<C, false>(xp, dp, bp, cp, WSH, SDT, yp, 0.f, AnL, c, bd, Dv);
  }
}

// ---------------- Fallback: fully sequential (no workspace) ----------------
__global__ __launch_bounds__(256) void ssm_seq(
    const float* __restrict__ x, const float* __restrict__ dt,
    const float* __restrict__ Bin, const float* __restrict__ Cin,
    const float* __restrict__ Alog, const float* __restrict__ Dp,
    float* __restrict__ y) {
  const int gid = blockIdx.x * 256 + threadIdx.x;
  if (gid >= kB * kD) return;
  const int b = gid / kD;
  const int d = gid % kD;

  float AnL[kN];
  const float* al = Alog + (size_t)d * kN;
#pragma unroll
  for (int n = 0; n < kN; ++n) AnL[n] = -__expf(al[n]) * kLog2e;

  float s[kN];
#pragma unroll
  for (int n = 0; n < kN; ++n) s[n] = 0.f;
  const float Dv = Dp[d];

  const float* xp = x + (size_t)b * kL * kD + d;
  const float* dp = dt + (size_t)b * kL * kD + d;
  const float* bp = Bin + (size_t)b * kL * kN;
  const float* cp = Cin + (size_t)b * kL * kN;
  float* yp = y + (size_t)b * kL * kD + d;

  for (int t = 0; t < kL; ++t) {
    const float dtv = dp[(size_t)t * kD];
    const float xv = xp[(size_t)t * kD];
    const float dtx = dtv * xv;
    float acc = 0.f;
#pragma unroll
    for (int n = 0; n < kN; ++n) {
      const float a = ex2(dtv * AnL[n]);
      s[n] = fmaf(a, s[n], dtx * bp[t * kN + n]);
      acc = fmaf(s[n], cp[t * kN + n], acc);
    }
    yp[(size_t)t * kD] = fmaf(xv, Dv, acc);
  }
}

template <int C>
void launch2(const float* x, const float* dtp, const float* Bin,
             const float* Cin, const float* Alog, const float* Dp, float* y,
             void* ws, hipStream_t stream) {
  __half2* WSH = reinterpret_cast<__half2*>(ws);       // C*kNH*kBD half2
  float* SDT = reinterpret_cast<float*>(WSH + (size_t)C * kNH * kBD);
  const int g = C * kB * kNDBLK;
  ssm2_partA<C><<<g, kTPB, 0, stream>>>(x, dtp, Bin, Alog, WSH, SDT);
  ssm2_partB<C><<<g, kTPB, 0, stream>>>(x, dtp, Bin, Cin, Alog, Dp, WSH, SDT,
                                        y);
}

}  // namespace

extern "C" void kernel_launch(void* const* d_in, const int* in_sizes, int n_in,
                              void* d_out, int out_size, void* d_ws, size_t ws_size,
                              hipStream_t stream) {
  const float* x    = (const float*)d_in[0];
  const float* dtp  = (const float*)d_in[1];
  const float* Bin  = (const float*)d_in[2];
  const float* Cin  = (const float*)d_in[3];
  const float* Alog = (const float*)d_in[4];
  const float* Dp   = (const float*)d_in[5];
  float* y = (float*)d_out;

  auto need = [](int C) {
    return (size_t)C * kNH * kBD * sizeof(__half2) +
           (size_t)C * kBD * sizeof(float);
  };

  if (ws_size >= need(64)) {
    launch2<64>(x, dtp, Bin, Cin, Alog, Dp, y, d_ws, stream);
  } else if (ws_size >= need(32)) {
    launch2<32>(x, dtp, Bin, Cin, Alog, Dp, y, d_ws, stream);
  } else {
    ssm_seq<<<(kB * kD + 255) / 256, 256, 0, stream>>>(x, dtp, Bin, Cin, Alog,
                                                       Dp, y);
  }
}